// Round 21
// baseline (73.977 us; speedup 1.0000x reference)
//
#include <hip/hip_runtime.h>

#define B_SZ 8192
#define XST 17  // xls row stride (floats), odd -> bank spread

// xls row map (per 16-col block, stride 17): 0-255 x; 256-257 out0; 258-261 out1;
// 262-269 out2; 270-285 out3; 286-317 out4; 318-381 out5 (final).

// ---------------- masks + unified COMPACTED params ----------
struct MaskArgs {
  const float* fm[6];
  const float* cp[6];
  const float* lr[6];
  float* out_masks;  // d_out base
  float4* cprm;      // compacted params {c10, ml0/8, ml1/8, fidx(xls row)}
  int* cnt;          // active count per stump (global stump idx)
  float* cstf;       // per-output 0.5*sum(ml)
};

__device__ __forceinline__ float wave_max(float v) {
#pragma unroll
  for (int o = 32; o > 0; o >>= 1) v = fmaxf(v, __shfl_xor(v, o));
  return v;
}
__device__ __forceinline__ float wave_sum(float v) {
#pragma unroll
  for (int o = 32; o > 0; o >>= 1) v += __shfl_xor(v, o);
  return v;
}

__global__ __launch_bounds__(64) void ndt_masks(MaskArgs a) {
  const int maskOff[6] = {524288, 524544, 525060, 526100, 528212, 532564};
  const int prmOff[6]  = {0, 256, 772, 1812, 3924, 8276};
  const int cstOff[6]  = {0, 1, 3, 7, 15, 31};
  const int exBase[6]  = {0, 256, 258, 262, 270, 286};  // xls row of extra f=256
  int bid = blockIdx.x, lane = threadIdx.x;
  int d = 0, s = bid, n = 1;
  while (s >= n) { s -= n; n <<= 1; ++d; }   // level d, stump s, n = 2^d
  int Fd = 256 + ((d > 0) ? n : 0);

  const float* fm = a.fm[d] + (size_t)s * Fd;
  float y[5];
#pragma unroll
  for (int j = 0; j < 5; ++j) {
    int f = lane + 64 * j;
    y[j] = (f < Fd) ? fm[f] * 0.5f : -3.0e38f;
  }
  float m = fmaxf(fmaxf(fmaxf(y[0], y[1]), fmaxf(y[2], y[3])), y[4]);
  m = wave_max(m);
#pragma unroll
  for (int j = 0; j < 5; ++j) y[j] -= m;

  // solve sum clip(y - tau, 0)^2 = 1; tau in [-1,0], decreasing in tau
  float lo = -1.f, hi = 0.f;
  for (int it = 0; it < 24; ++it) {
    float tau = 0.5f * (lo + hi);
    float ss = 0.f;
#pragma unroll
    for (int j = 0; j < 5; ++j) {
      float v = fmaxf(y[j] - tau, 0.f);
      ss = __builtin_fmaf(v, v, ss);
    }
    ss = wave_sum(ss);
    if (ss >= 1.f) lo = tau; else hi = tau;
  }
  float tau = 0.5f * (lo + hi);

  float* mo = a.out_masks + maskOff[d] + (size_t)s * Fd;
  const float* cp = a.cp[d] + (size_t)s * Fd * 2;
  const float* lr = a.lr[d] + (size_t)s * Fd * 2;
  float4* cpr = a.cprm + prmOff[d] + (size_t)s * Fd;
  int exB = exBase[d];
  float sum0 = 0.f, sum1 = 0.f;
  int base = 0;
#pragma unroll
  for (int j = 0; j < 5; ++j) {
    int f = lane + 64 * j;
    bool in = (f < Fd);
    float v = fmaxf(y[j] - tau, 0.f);
    float mk = v * v;
    float c10 = 0.f, ml0 = 0.f, ml1 = 0.f;
    if (in) {
      mo[f] = mk;
      float c0 = cp[2 * f], c1 = cp[2 * f + 1];
      ml0 = lr[2 * f] * mk;
      ml1 = lr[2 * f + 1] * mk;
      c10 = c1 - c0;
      sum0 += ml0;
      sum1 += ml1;
    }
    bool act = in && (v > 0.f);
    unsigned long long bm = __ballot(act);
    int pre = __popcll(bm & ((1ull << lane) - 1ull));
    if (act) {
      int fidx = (f < 256) ? f : (exB + f - 256);
      cpr[base + pre] =
          make_float4(c10, ml0 * 0.125f, ml1 * 0.125f, __int_as_float(fidx));
    }
    base += __popcll(bm);
  }
  sum0 = wave_sum(sum0);
  sum1 = wave_sum(sum1);
  if (lane == 0) {
    a.cstf[2 * (cstOff[d] + s)] = 0.5f * sum0;
    a.cstf[2 * (cstOff[d] + s) + 1] = 0.5f * sum1;
    a.cnt[cstOff[d] + s] = base;
  }
}

// 2-elem entmax15 closed form (scaled): t = c10 - x; tc = clamp(t,-2,2);
// e' = tc*sqrt(8 - tc^2) = 8*e. The 1/8 is folded into ml at build time.
__device__ __forceinline__ float entpair(float c10, float xv) {
  float t = c10 - xv;
  float tc = __builtin_amdgcn_fmed3f(t, -2.f, 2.f);
  float u = __builtin_fmaf(tc, -tc, 8.0f);
  return tc * __builtin_amdgcn_sqrtf(u);
}

// ---------------- one level: wave = 4 entries x 16 cols, uniform j-list ----------
// 512 thr = 8 waves; lane = (e = lane>>4, c = lane&15). Per wave-iter: lanes e=0..3
// read 4 CONSECUTIVE param entries (64B, 1-2 lines); gather reads 4 rows x 16
// consecutive dwords at stride 17 (~conflict-free). Entry-reduce = 2 shfl_xor.
// N>=8: wave owns N/8 stumps, 1 barrier. N<8: 8/N waves split a stump via pbuf.
template <int N, int FD>
__device__ __forceinline__ void ndt_level(const float4* __restrict__ cp,
                                          const int* __restrict__ cN,
                                          const float* __restrict__ cs,
                                          int outRow, int w, int lane,
                                          float* __restrict__ xls,
                                          float (*__restrict__ pbuf)[2][16]) {
  int e = lane >> 4, c = lane & 15;
  if (N >= 8) {
#pragma unroll
    for (int k = 0; k < N / 8; ++k) {
      int s = w + 8 * k;
      int nc = cN[s];
      const float4* ps = cp + (size_t)s * FD;
      float a0 = 0.f, a1 = 0.f;
#pragma unroll 2
      for (int j = 0; j < nc; j += 4) {
        int jj = j + e;
        if (jj < nc) {
          float4 p = ps[jj];
          int row = __float_as_int(p.w);
          float xv = xls[row * XST + c];
          float ee = entpair(p.x, xv);
          a0 = __builtin_fmaf(ee, p.y, a0);
          a1 = __builtin_fmaf(-ee, p.z, a1);
        }
      }
      a0 += __shfl_xor(a0, 16);
      a0 += __shfl_xor(a0, 32);
      a1 += __shfl_xor(a1, 16);
      a1 += __shfl_xor(a1, 32);
      if (e == 0)
        xls[(outRow + 2 * s) * XST + c] = a0 + cs[2 * s];
      else if (e == 1)
        xls[(outRow + 2 * s + 1) * XST + c] = a1 + cs[2 * s + 1];
    }
    __syncthreads();
  } else {
    constexpr int WPS = 8 / N;
    int s = w / WPS, slice = w % WPS;
    int nc = cN[s];
    const float4* ps = cp + (size_t)s * FD;
    int jlo = slice * nc / WPS, jhi = (slice + 1) * nc / WPS;
    float a0 = 0.f, a1 = 0.f;
#pragma unroll 2
    for (int j = jlo; j < jhi; j += 4) {
      int jj = j + e;
      if (jj < jhi) {
        float4 p = ps[jj];
        int row = __float_as_int(p.w);
        float xv = xls[row * XST + c];
        float ee = entpair(p.x, xv);
        a0 = __builtin_fmaf(ee, p.y, a0);
        a1 = __builtin_fmaf(-ee, p.z, a1);
      }
    }
    a0 += __shfl_xor(a0, 16);
    a0 += __shfl_xor(a0, 32);
    a1 += __shfl_xor(a1, 16);
    a1 += __shfl_xor(a1, 32);
    if (e == 0)
      pbuf[w][0][c] = a0;
    else if (e == 1)
      pbuf[w][1][c] = a1;
    __syncthreads();
    int tid = w * 64 + lane;
    if (tid < 2 * N * 16) {
      int o = tid >> 4, cc = tid & 15;
      int s2 = o >> 1, par = o & 1;
      float v = cs[o];
#pragma unroll
      for (int k = 0; k < WPS; ++k) v += pbuf[s2 * WPS + k][par][cc];
      xls[(outRow + o) * XST + cc] = v;
    }
    __syncthreads();
  }
}

// ---------------- unified kernel: all 6 levels, 16 cols per block ----------------
__global__ __launch_bounds__(512, 4) void ndt_all(const float* __restrict__ x,
                                                  const float4* __restrict__ cprm,
                                                  const int* __restrict__ cnt,
                                                  const float* __restrict__ cstf,
                                                  float* __restrict__ out) {
  __shared__ float xls[382 * XST];
  __shared__ float pbuf[8][2][16];
  int tid = threadIdx.x;
  int w = tid >> 6, lane = tid & 63;
  int b0 = blockIdx.x * 16;
  // stage x (cols b0..b0+15): thread (c, seg) reads rows seg+32j (coalesced 2
  // lines/wave-instr); stride-17 writes spread all 32 banks (gcd(17,32)=1).
  {
    int c = tid >> 5, seg = tid & 31;
    const float* xp = x + (size_t)(b0 + c) * 256 + seg;
#pragma unroll
    for (int j = 0; j < 8; ++j) xls[(seg + 32 * j) * XST + c] = xp[32 * j];
  }
  __syncthreads();
  ndt_level<1, 256>(cprm, cnt, cstf, 256, w, lane, xls, pbuf);
  ndt_level<2, 258>(cprm + 256, cnt + 1, cstf + 2, 258, w, lane, xls, pbuf);
  ndt_level<4, 260>(cprm + 772, cnt + 3, cstf + 6, 262, w, lane, xls, pbuf);
  ndt_level<8, 264>(cprm + 1812, cnt + 7, cstf + 14, 270, w, lane, xls, pbuf);
  ndt_level<16, 272>(cprm + 3924, cnt + 15, cstf + 30, 286, w, lane, xls, pbuf);
  ndt_level<32, 288>(cprm + 8276, cnt + 31, cstf + 62, 318, w, lane, xls, pbuf);
  // coalesced final write: col c's 64 outputs contiguous in out
  {
    int c = tid >> 5, oo = (tid & 31) * 2;
    float2 v = make_float2(xls[(318 + oo) * XST + c], xls[(319 + oo) * XST + c]);
    *(float2*)(out + (size_t)(b0 + c) * 64 + oo) = v;
  }
}

extern "C" void kernel_launch(void* const* d_in, const int* in_sizes, int n_in,
                              void* d_out, int out_size, void* d_ws, size_t ws_size,
                              hipStream_t stream) {
  const float* x = (const float*)d_in[0];
  float* out = (float*)d_out;
  float* wsf = (float*)d_ws;

  // ws layout (float offsets)
  float4* cprm = (float4*)(wsf + 2575872);  // 17492 float4 (compacted)
  float* cstf = wsf + 2645840;              // 126 floats
  int* cnt = (int*)(wsf + 2645966);         // 63 ints

  MaskArgs ma;
  for (int d = 0; d < 6; ++d) {
    ma.fm[d] = (const float*)d_in[1 + 3 * d];
    ma.cp[d] = (const float*)d_in[2 + 3 * d];
    ma.lr[d] = (const float*)d_in[3 + 3 * d];
  }
  ma.out_masks = out;
  ma.cprm = cprm;
  ma.cnt = cnt;
  ma.cstf = cstf;
  hipLaunchKernelGGL(ndt_masks, dim3(63), dim3(64), 0, stream, ma);

  // all 6 levels in one kernel: 512 blocks x 512 thr, 16 cols/block
  hipLaunchKernelGGL(ndt_all, dim3(B_SZ / 16), dim3(512), 0, stream,
                     x, cprm, cnt, cstf, out);
}

// Round 22
// 37.616 us; speedup vs baseline: 1.9666x; 1.9666x over previous
//
#include <hip/hip_runtime.h>

#define B_SZ 8192
#define XST 17  // xls row stride (floats): 16 cols + 1 pad, odd -> bank spread

// xls row map (per 16-col block, stride 17): 0-255 x; 256-257 out0; 258-261 out1;
// 262-269 out2; 270-285 out3; 286-317 out4; 318-381 out5 (final).

// ---------------- masks + unified COMPACTED params ----------
struct MaskArgs {
  const float* fm[6];
  const float* cp[6];
  const float* lr[6];
  float* out_masks;  // d_out base
  float4* cprm;      // compacted params {c10, ml0/8, ml1/8, fidx(xls row)}
  int* cnt;          // active count per stump (global stump idx)
  float* cstf;       // per-output 0.5*sum(ml)
};

__device__ __forceinline__ float wave_max(float v) {
#pragma unroll
  for (int o = 32; o > 0; o >>= 1) v = fmaxf(v, __shfl_xor(v, o));
  return v;
}
__device__ __forceinline__ float wave_sum(float v) {
#pragma unroll
  for (int o = 32; o > 0; o >>= 1) v += __shfl_xor(v, o);
  return v;
}

__global__ __launch_bounds__(64) void ndt_masks(MaskArgs a) {
  const int maskOff[6] = {524288, 524544, 525060, 526100, 528212, 532564};
  const int prmOff[6]  = {0, 256, 772, 1812, 3924, 8276};
  const int cstOff[6]  = {0, 1, 3, 7, 15, 31};
  const int exBase[6]  = {0, 256, 258, 262, 270, 286};  // xls row of extra f=256
  int bid = blockIdx.x, lane = threadIdx.x;
  int d = 0, s = bid, n = 1;
  while (s >= n) { s -= n; n <<= 1; ++d; }   // level d, stump s, n = 2^d
  int Fd = 256 + ((d > 0) ? n : 0);

  const float* fm = a.fm[d] + (size_t)s * Fd;
  float y[5];
#pragma unroll
  for (int j = 0; j < 5; ++j) {
    int f = lane + 64 * j;
    y[j] = (f < Fd) ? fm[f] * 0.5f : -3.0e38f;
  }
  float m = fmaxf(fmaxf(fmaxf(y[0], y[1]), fmaxf(y[2], y[3])), y[4]);
  m = wave_max(m);
#pragma unroll
  for (int j = 0; j < 5; ++j) y[j] -= m;

  // solve sum clip(y - tau, 0)^2 = 1; tau in [-1,0], decreasing in tau
  float lo = -1.f, hi = 0.f;
  for (int it = 0; it < 24; ++it) {
    float tau = 0.5f * (lo + hi);
    float ss = 0.f;
#pragma unroll
    for (int j = 0; j < 5; ++j) {
      float v = fmaxf(y[j] - tau, 0.f);
      ss = __builtin_fmaf(v, v, ss);
    }
    ss = wave_sum(ss);
    if (ss >= 1.f) lo = tau; else hi = tau;
  }
  float tau = 0.5f * (lo + hi);

  float* mo = a.out_masks + maskOff[d] + (size_t)s * Fd;
  const float* cp = a.cp[d] + (size_t)s * Fd * 2;
  const float* lr = a.lr[d] + (size_t)s * Fd * 2;
  float4* cpr = a.cprm + prmOff[d] + (size_t)s * Fd;
  int exB = exBase[d];
  float sum0 = 0.f, sum1 = 0.f;
  int base = 0;
#pragma unroll
  for (int j = 0; j < 5; ++j) {
    int f = lane + 64 * j;
    bool in = (f < Fd);
    float v = fmaxf(y[j] - tau, 0.f);
    float mk = v * v;
    float c10 = 0.f, ml0 = 0.f, ml1 = 0.f;
    if (in) {
      mo[f] = mk;
      float c0 = cp[2 * f], c1 = cp[2 * f + 1];
      ml0 = lr[2 * f] * mk;
      ml1 = lr[2 * f + 1] * mk;
      c10 = c1 - c0;
      sum0 += ml0;
      sum1 += ml1;
    }
    bool act = in && (v > 0.f);
    unsigned long long bm = __ballot(act);
    int pre = __popcll(bm & ((1ull << lane) - 1ull));
    if (act) {
      int fidx = (f < 256) ? f : (exB + f - 256);
      cpr[base + pre] =
          make_float4(c10, ml0 * 0.125f, ml1 * 0.125f, __int_as_float(fidx));
    }
    base += __popcll(bm);
  }
  sum0 = wave_sum(sum0);
  sum1 = wave_sum(sum1);
  if (lane == 0) {
    a.cstf[2 * (cstOff[d] + s)] = 0.5f * sum0;
    a.cstf[2 * (cstOff[d] + s) + 1] = 0.5f * sum1;
    a.cnt[cstOff[d] + s] = base;
  }
}

// 2-elem entmax15 closed form (scaled): t = c10 - x; tc = clamp(t,-2,2);
// e' = tc*sqrt(8 - tc^2) = 8*e. The 1/8 is folded into ml at build time.
__device__ __forceinline__ float entpair(float c10, float xv) {
  float t = c10 - xv;
  float tc = __builtin_amdgcn_fmed3f(t, -2.f, 2.f);
  float u = __builtin_fmaf(tc, -tc, 8.0f);
  return tc * __builtin_amdgcn_sqrtf(u);
}

// ---------------- one level (R18 skeleton, 2 cols per lane) ----------------
// 512 thr = 64 groups x 8 lanes; lane l of group g handles cols l and l+8.
// SPG = 64/N groups per stump split the stump's compacted list; one param
// dwordx4 per j feeds BOTH cols (2 pair-ops). Partials combine via pbuf;
// outputs -> xls rows [outRow, outRow+2N), becoming next level's extras.
template <int N, int FD>
__device__ __forceinline__ void ndt_level(const float4* __restrict__ cp,
                                          const int* __restrict__ cN,
                                          const float* __restrict__ cs,
                                          int outRow, int g, int l,
                                          float* __restrict__ pbuf,
                                          float* __restrict__ xls) {
  constexpr int SPG = 64 / N;
  int s = g / SPG, slice = g - s * SPG;
  int nc = cN[s];
  const float4* ps = cp + (size_t)s * FD;
  float a00 = 0.f, a10 = 0.f, a01 = 0.f, a11 = 0.f;
  int jlo = slice * nc / SPG, jhi = (slice + 1) * nc / SPG;
#pragma unroll 4
  for (int j = jlo; j < jhi; ++j) {
    float4 p = ps[j];
    int row = __float_as_int(p.w);
    float xv0 = xls[row * XST + l];
    float xv1 = xls[row * XST + l + 8];
    float e0 = entpair(p.x, xv0);
    float e1 = entpair(p.x, xv1);
    a00 = __builtin_fmaf(e0, p.y, a00);
    a10 = __builtin_fmaf(-e0, p.z, a10);
    a01 = __builtin_fmaf(e1, p.y, a01);
    a11 = __builtin_fmaf(-e1, p.z, a11);
  }
  // pbuf layout: [g][2 outs][16 cols] = g*32 + par*16 + c
  pbuf[g * 32 + l] = a00;
  pbuf[g * 32 + l + 8] = a01;
  pbuf[g * 32 + 16 + l] = a10;
  pbuf[g * 32 + 16 + l + 8] = a11;
  __syncthreads();
  int tid = g * 8 + l;
  for (int t = tid; t < 2 * N * 16; t += 512) {
    int o = t >> 4, cc = t & 15;
    int s2 = o >> 1, par = o & 1;
    float v = cs[o];
#pragma unroll
    for (int k = 0; k < SPG; ++k)
      v += pbuf[(s2 * SPG + k) * 32 + par * 16 + cc];
    xls[(outRow + o) * XST + cc] = v;
  }
  __syncthreads();
}

// ---------------- unified kernel: all 6 levels, 16 cols per block ----------------
__global__ __launch_bounds__(512, 4) void ndt_all(const float* __restrict__ x,
                                                  const float4* __restrict__ cprm,
                                                  const int* __restrict__ cnt,
                                                  const float* __restrict__ cstf,
                                                  float* __restrict__ out) {
  __shared__ float xls[382 * XST];
  __shared__ float pbuf[64 * 32];
  int tid = threadIdx.x;
  int g = tid >> 3, l = tid & 7;
  int b0 = blockIdx.x * 16;
  // stage x (cols b0..b0+15): thread (c, seg) reads rows seg+32j (coalesced);
  // stride-17 writes spread all 32 banks (gcd(17,32)=1).
  {
    int c = tid >> 5, seg = tid & 31;
    const float* xp = x + (size_t)(b0 + c) * 256 + seg;
#pragma unroll
    for (int j = 0; j < 8; ++j) xls[(seg + 32 * j) * XST + c] = xp[32 * j];
  }
  __syncthreads();
  ndt_level<1, 256>(cprm, cnt, cstf, 256, g, l, pbuf, xls);
  ndt_level<2, 258>(cprm + 256, cnt + 1, cstf + 2, 258, g, l, pbuf, xls);
  ndt_level<4, 260>(cprm + 772, cnt + 3, cstf + 6, 262, g, l, pbuf, xls);
  ndt_level<8, 264>(cprm + 1812, cnt + 7, cstf + 14, 270, g, l, pbuf, xls);
  ndt_level<16, 272>(cprm + 3924, cnt + 15, cstf + 30, 286, g, l, pbuf, xls);
  ndt_level<32, 288>(cprm + 8276, cnt + 31, cstf + 62, 318, g, l, pbuf, xls);
  // coalesced final write: col c's 64 outputs contiguous in out
  {
    int c = tid >> 5, oo = (tid & 31) * 2;
    float2 v = make_float2(xls[(318 + oo) * XST + c], xls[(319 + oo) * XST + c]);
    *(float2*)(out + (size_t)(b0 + c) * 64 + oo) = v;
  }
}

extern "C" void kernel_launch(void* const* d_in, const int* in_sizes, int n_in,
                              void* d_out, int out_size, void* d_ws, size_t ws_size,
                              hipStream_t stream) {
  const float* x = (const float*)d_in[0];
  float* out = (float*)d_out;
  float* wsf = (float*)d_ws;

  // ws layout (float offsets)
  float4* cprm = (float4*)(wsf + 2575872);  // 17492 float4 (compacted)
  float* cstf = wsf + 2645840;              // 126 floats
  int* cnt = (int*)(wsf + 2645966);         // 63 ints

  MaskArgs ma;
  for (int d = 0; d < 6; ++d) {
    ma.fm[d] = (const float*)d_in[1 + 3 * d];
    ma.cp[d] = (const float*)d_in[2 + 3 * d];
    ma.lr[d] = (const float*)d_in[3 + 3 * d];
  }
  ma.out_masks = out;
  ma.cprm = cprm;
  ma.cnt = cnt;
  ma.cstf = cstf;
  hipLaunchKernelGGL(ndt_masks, dim3(63), dim3(64), 0, stream, ma);

  // all 6 levels in one kernel: 512 blocks x 512 thr, 16 cols/block
  hipLaunchKernelGGL(ndt_all, dim3(B_SZ / 16), dim3(512), 0, stream,
                     x, cprm, cnt, cstf, out);
}